// Round 16
// baseline (1867.155 us; speedup 1.0000x reference)
//
#include <hip/hip_runtime.h>

// RNN: B=64, T=512, I=1024, H=1024, fp32 in/out.
// Phase 0: transpose-convert Wx/Wh -> bf16 [N][K] in ws.
// Phase 1: xproj = x @ Wx + bx + bh (bf16 MFMA, fp32 accum) -> d_out.
// Phase 2: persistent MFMA scan, 64 blocks x 512 thr = 8 clusters x 8 members.
//   R16 change: NO LDS h-tile. Post-#C each wave loads its MFMA A-fragments
//   DIRECTLY from hbuf (MALL) into registers -- one self-contained asm
//   {4x dwordx4 sc0sc1 + vmcnt(0)}. Deletes: #D barrier, staging writes,
//   af LDS reads, and both bank-conflict sources (was ~1000 conflict-cy/step).
//   To keep the af drain clean (R13 lesson), every wave drains its publish
//   with vmcnt(0) BEFORE #B (wave-parallel), and the HBM out-store/xp-load
//   issue AFTER the af asm, flying under the next step's MFMA+reduce.
//   Barriers/step: #B (publishes acked), #C (flags observed), #P (partials).

#define Bdim 64
#define Tdim 512
#define Idim 1024
#define Hdim 1024
#define Mdim (Bdim * Tdim)  // 32768

typedef __attribute__((ext_vector_type(8))) short bf16x8;
typedef __attribute__((ext_vector_type(4))) float f32x4;
typedef __attribute__((ext_vector_type(4))) unsigned int u32x4;

__device__ __forceinline__ float tanh_fast(float x) {
  float e = __expf(2.0f * x);
  return 1.0f - 2.0f / (e + 1.0f);
}
__device__ __forceinline__ unsigned int f2bf(float f) {
  unsigned int u = __float_as_uint(f);
  return (u + 0x7FFFu + ((u >> 16) & 1u)) >> 16;  // RNE
}
__device__ __forceinline__ unsigned int pack2(float lo, float hi) {
  return f2bf(lo) | (f2bf(hi) << 16);
}

// ---------------- Phase 0: fp32 [K][N] -> bf16 transposed [N][K] -------------
__global__ __launch_bounds__(256) void cvt_transpose(
    const float* __restrict__ src, unsigned short* __restrict__ dst) {
  __shared__ float t[32][33];
  const int bx = blockIdx.x * 32;
  const int by = blockIdx.y * 32;
  const int ty = threadIdx.x >> 3;
  const int tx = threadIdx.x & 7;
  float4 v = *(const float4*)&src[(size_t)(by + ty) * 1024 + bx + tx * 4];
  t[ty][tx * 4 + 0] = v.x; t[ty][tx * 4 + 1] = v.y;
  t[ty][tx * 4 + 2] = v.z; t[ty][tx * 4 + 3] = v.w;
  __syncthreads();
  ushort4 o;
  o.x = (unsigned short)f2bf(t[tx * 4 + 0][ty]);
  o.y = (unsigned short)f2bf(t[tx * 4 + 1][ty]);
  o.z = (unsigned short)f2bf(t[tx * 4 + 2][ty]);
  o.w = (unsigned short)f2bf(t[tx * 4 + 3][ty]);
  *(ushort4*)&dst[(size_t)(bx + ty) * 1024 + by + tx * 4] = o;
}

// ---------------- Phase 1: bf16 MFMA GEMM, 128x128 tile, BK=32 ---------------
__global__ __launch_bounds__(256) void xg_mfma(
    const float* __restrict__ X,            // [M][K] fp32
    const unsigned short* __restrict__ WxT, // [N][K] bf16
    const float* __restrict__ bx, const float* __restrict__ bh,
    float* __restrict__ C) {                // [M][N] fp32
  __shared__ char sAB[16384] __attribute__((aligned(16)));
  char* sA = sAB;
  char* sB = sAB + 8192;
  const int tid = threadIdx.x;
  const int m0 = blockIdx.y * 128;
  const int n0 = blockIdx.x * 128;
  const int w = tid >> 6, l = tid & 63;
  const int wm = (w >> 1) * 64, wn = (w & 1) * 64;
  const int r2 = tid >> 1, kh = tid & 1;

  f32x4 acc[4][4];
#pragma unroll
  for (int i = 0; i < 4; ++i)
#pragma unroll
    for (int j = 0; j < 4; ++j) acc[i][j] = (f32x4){0.f, 0.f, 0.f, 0.f};

  for (int k0 = 0; k0 < Idim; k0 += 32) {
    const float* xa = &X[(size_t)(m0 + r2) * Idim + k0 + kh * 16];
    float4 a0 = *(const float4*)(xa + 0), a1 = *(const float4*)(xa + 4);
    float4 a2 = *(const float4*)(xa + 8), a3 = *(const float4*)(xa + 12);
    const char* wb = (const char*)&WxT[(size_t)(n0 + r2) * Idim + k0 + kh * 16];
    u32x4 b0 = *(const u32x4*)wb;
    u32x4 b1 = *(const u32x4*)(wb + 16);
    __syncthreads();
    u32x4 pa0 = {pack2(a0.x, a0.y), pack2(a0.z, a0.w),
                 pack2(a1.x, a1.y), pack2(a1.z, a1.w)};
    u32x4 pa1 = {pack2(a2.x, a2.y), pack2(a2.z, a2.w),
                 pack2(a3.x, a3.y), pack2(a3.z, a3.w)};
    const int sw = (r2 & 7) << 4;
    const int rb = r2 * 64 + kh * 32;
    *(u32x4*)(sA + ((rb + 0) ^ sw)) = pa0;
    *(u32x4*)(sA + ((rb + 16) ^ sw)) = pa1;
    *(u32x4*)(sB + ((rb + 0) ^ sw)) = b0;
    *(u32x4*)(sB + ((rb + 16) ^ sw)) = b1;
    __syncthreads();
    bf16x8 af[4], bf[4];
#pragma unroll
    for (int i = 0; i < 4; ++i) {
      int ra = wm + i * 16 + (l & 15);
      af[i] = *(const bf16x8*)(sA + ((ra * 64 + (l >> 4) * 16) ^ ((ra & 7) << 4)));
      int rn = wn + i * 16 + (l & 15);
      bf[i] = *(const bf16x8*)(sB + ((rn * 64 + (l >> 4) * 16) ^ ((rn & 7) << 4)));
    }
#pragma unroll
    for (int i = 0; i < 4; ++i)
#pragma unroll
      for (int j = 0; j < 4; ++j)
        acc[i][j] = __builtin_amdgcn_mfma_f32_16x16x32_bf16(af[i], bf[j],
                                                            acc[i][j], 0, 0, 0);
  }
  float bias[4];
#pragma unroll
  for (int j = 0; j < 4; ++j) {
    int cc = n0 + wn + j * 16 + (l & 15);
    bias[j] = bx[cc] + bh[cc];
  }
#pragma unroll
  for (int i = 0; i < 4; ++i) {
    int rbase = m0 + wm + i * 16 + (l >> 4) * 4;
#pragma unroll
    for (int j = 0; j < 4; ++j) {
      int cc = n0 + wn + j * 16 + (l & 15);
#pragma unroll
      for (int r = 0; r < 4; ++r)
        C[(size_t)(rbase + r) * Hdim + cc] = acc[i][j][r] + bias[j];
    }
  }
}

// ---------------- flag clear (agent stores -> MALL) --------------------------
__global__ void clear_flags(unsigned int* flags) {
  __hip_atomic_store(&flags[threadIdx.x], 0u, __ATOMIC_RELAXED,
                     __HIP_MEMORY_SCOPE_AGENT);
}

// ---------------- Phase 2: persistent MFMA scan (direct-reg A) ---------------
// flags: [c*32 + m], one 128B line per cluster. hbuf: [2 par][64 b][512 cp].
__global__ __launch_bounds__(512, 2) void rnn_scan(
    const unsigned short* __restrict__ WhT,  // [N=1024][K=1024] bf16
    float* __restrict__ out,                 // [B][T][H]: xproj in, h out
    float* __restrict__ hlast,               // [B][H]
    unsigned int* hbuf,                      // ws: 256 KB payload
    unsigned int* flags) {                   // ws: 256 dwords
  const int bid = blockIdx.x;
  const int c = bid & 7;   // cluster: batches c*8..+8
  const int m = bid >> 3;  // member: cols m*128..+128
  const int tid = threadIdx.x;
  const int w = tid >> 6;  // wave: k-slice w*128..+128; batch row w
  const int l = tid & 63;
  const int n0 = m * 128;

  __shared__ char smp[33792] __attribute__((aligned(16)));  // [8w][8nt][33][16B]

  // B-frags: Wh[k=w*128..+128][cols n0..+128] = 32 x bf16x8 (unified reg file)
  bf16x8 bfrag[32];
  {
    const int kb = (w << 7) + ((l >> 4) << 3);
    const int col = n0 + (l & 15);
#pragma unroll
    for (int nt = 0; nt < 8; ++nt)
#pragma unroll
      for (int kt = 0; kt < 4; ++kt)
        bfrag[nt * 4 + kt] =
            *(const bf16x8*)&WhT[(size_t)(col + nt * 16) * 1024 + kb + kt * 32];
  }
#pragma unroll
  for (int i = 0; i < 32; ++i) asm volatile("" : "+v"(bfrag[i]));

  const int c0 = l * 2;  // col pair this thread finishes
  const int b_abs = c * 8 + w;
  const int nt0 = c0 >> 4;
  const int lane0 = ((w >> 2) << 4) | (c0 & 15);
  const int regb = (w & 3) * 4;
  const size_t orow = (size_t)b_abs * ((size_t)Tdim * Hdim) + n0 + c0;
  unsigned int* const myflag = &flags[c * 32 + m];
  const unsigned int* const pollf = &flags[c * 32 + (l & 7)];
  // A-frag source: row = cluster batch (l&7), k-slice of wave w
  const char* const afbase = (const char*)hbuf +
      (size_t)(c * 8 + (l & 7)) * 2048 + (size_t)((w << 8) + ((l >> 4) << 4));

  float2 xp = *(const float2*)&out[orow];  // xproj t=0
  bf16x8 af0 = {}, af1 = {}, af2 = {}, af3 = {};

  for (int t = 0; t < Tdim; ++t) {
    float sum0 = 0.f, sum1 = 0.f;
    if (t > 0) {
      // ---- MFMA from loop-carried af regs (loaded at end of prev iter) ----
#pragma unroll
      for (int nt = 0; nt < 8; ++nt) {
        f32x4 a = {0.f, 0.f, 0.f, 0.f};
        a = __builtin_amdgcn_mfma_f32_16x16x32_bf16(af0, bfrag[nt * 4 + 0], a, 0, 0, 0);
        a = __builtin_amdgcn_mfma_f32_16x16x32_bf16(af1, bfrag[nt * 4 + 1], a, 0, 0, 0);
        a = __builtin_amdgcn_mfma_f32_16x16x32_bf16(af2, bfrag[nt * 4 + 2], a, 0, 0, 0);
        a = __builtin_amdgcn_mfma_f32_16x16x32_bf16(af3, bfrag[nt * 4 + 3], a, 0, 0, 0);
        if (l < 32)  // lanes 32-63 hold duplicate batch rows: discard
          *(f32x4*)(smp + (((w * 8 + nt) * 33 + l) << 4)) = a;
      }
      asm volatile("s_waitcnt lgkmcnt(0)" ::: "memory");
      __builtin_amdgcn_s_barrier();  // #P: partials visible
      asm volatile("" ::: "memory");
#pragma unroll
      for (int w8 = 0; w8 < 8; ++w8) {
        const char* p = smp + (((w8 * 8 + nt0) * 33 + lane0) << 4) + regb;
        sum0 += *(const float*)p;
        sum1 += *(const float*)(p + 16);
      }
    }
    float h0 = tanh_fast(xp.x + sum0);
    float h1 = tanh_fast(xp.y + sum1);
    if (t == Tdim - 1) {
      *(float2*)&out[orow + (size_t)t * Hdim] = make_float2(h0, h1);
      *(float2*)&hlast[(size_t)b_abs * Hdim + n0 + c0] = make_float2(h0, h1);
      break;
    }
    const int par = (t + 1) & 1;
    const unsigned int tp1 = (unsigned int)(t + 1);
    // ---- publish, drained per-wave (queue holds ONLY the publish) ----
    {
      unsigned int* pubp = hbuf + (size_t)par * 32768 + (size_t)b_abs * 512 +
                           m * 64 + l;
      unsigned int pv = pack2(h0, h1);
      asm volatile(
          "global_store_dword %0, %1, off sc0 sc1\n\ts_waitcnt vmcnt(0)"
          :: "v"(pubp), "v"(pv) : "memory");
    }
    __builtin_amdgcn_s_barrier();  // #B: all waves' publishes acked at MALL
    asm volatile("" ::: "memory");
    if (tid == 0)
      __hip_atomic_store(myflag, tp1, __ATOMIC_RELAXED,
                         __HIP_MEMORY_SCOPE_AGENT);
    if (w == 7) {  // poll 8 member flags (one 128B line); clean queue
      for (;;) {
        unsigned int v;
        asm volatile(
            "global_load_dword %0, %1, off sc0 sc1\n\ts_waitcnt vmcnt(0)"
            : "=v"(v) : "v"(pollf) : "memory");
        if (__ballot(v >= tp1) == ~0ull) break;
        __builtin_amdgcn_s_sleep(1);
      }
    }
    __builtin_amdgcn_s_barrier();  // #C: flags observed
    asm volatile("" ::: "memory");
    // ---- A-frags for t+1 DIRECT from MALL into registers (no LDS) ----
    {
      const char* srcp = afbase + (size_t)par * 131072;
      asm volatile(
          "global_load_dwordx4 %0, %4, off sc0 sc1\n\t"
          "global_load_dwordx4 %1, %4, off offset:64 sc0 sc1\n\t"
          "global_load_dwordx4 %2, %4, off offset:128 sc0 sc1\n\t"
          "global_load_dwordx4 %3, %4, off offset:192 sc0 sc1\n\t"
          "s_waitcnt vmcnt(0)"
          : "=&v"(af0), "=&v"(af1), "=&v"(af2), "=&v"(af3)
          : "v"(srcp) : "memory");
      __builtin_amdgcn_sched_barrier(0);
    }
    // ---- HBM ops issued last: fly under next step's MFMA + reduce ----
    *(float2*)&out[orow + (size_t)t * Hdim] = make_float2(h0, h1);
    xp = *(const float2*)&out[orow + (size_t)(t + 1) * Hdim];
  }
}

extern "C" void kernel_launch(void* const* d_in, const int* in_sizes, int n_in,
                              void* d_out, int out_size, void* d_ws,
                              size_t ws_size, hipStream_t stream) {
  const float* x  = (const float*)d_in[0];
  const float* Wx = (const float*)d_in[1];
  const float* bx = (const float*)d_in[2];
  const float* Wh = (const float*)d_in[3];
  const float* bh = (const float*)d_in[4];
  float* out = (float*)d_out;
  float* hlast = out + (size_t)Bdim * Tdim * Hdim;
  unsigned int* flags = (unsigned int*)d_ws;                       // 1 KB
  unsigned int* hbuf = (unsigned int*)((char*)d_ws + 4096);        // 256 KB
  unsigned short* WxT = (unsigned short*)((char*)d_ws + 4096 + 262144);
  unsigned short* WhT = (unsigned short*)((char*)d_ws + 4096 + 262144 + 2097152);

  clear_flags<<<1, dim3(256), 0, stream>>>(flags);
  dim3 gt(32, 32);
  cvt_transpose<<<gt, dim3(256), 0, stream>>>(Wx, WxT);
  cvt_transpose<<<gt, dim3(256), 0, stream>>>(Wh, WhT);
  xg_mfma<<<dim3(Hdim / 128, Mdim / 128), dim3(256), 0, stream>>>(x, WxT, bx,
                                                                  bh, out);
  rnn_scan<<<dim3(64), dim3(512), 0, stream>>>(WhT, out, hlast, hbuf, flags);
}

// Round 17
// 1604.890 us; speedup vs baseline: 1.1634x; 1.1634x over previous
//
#include <hip/hip_runtime.h>

// RNN: B=64, T=512, I=1024, H=1024, fp32 in/out.
// Phase 0: transpose-convert Wx/Wh -> bf16 [N][K] in ws (two tiny kernels).
// Phase 1+2 FUSED in one launch (1088 blocks x 512 thr):
//   bids 0..63   : persistent MFMA scan (R9-fallback protocol, proven 1354us),
//                  placed first -> resident immediately; gated on xproj
//                  chunk-counters at t = 0/127/255/383.
//   bids 64..1087: 1024 GEMM blocks, 128x256 tile each (xproj = x@Wx+bx+bh).
//                  C stored with sc0sc1 (MALL-visible), vmcnt(0), then
//                  atomicAdd(counter[t-chunk]). 256 tiles per chunk.
//   Scan consumes chunk 0 only after ~330us of scan work -> GEMM fully
//   overlaps. No deadlock: scan waits only on GEMM forward progress.

#define Bdim 64
#define Tdim 512
#define Idim 1024
#define Hdim 1024
#define Mdim (Bdim * Tdim)  // 32768

typedef __attribute__((ext_vector_type(8))) short bf16x8;
typedef __attribute__((ext_vector_type(4))) float f32x4;
typedef __attribute__((ext_vector_type(4))) unsigned int u32x4;

__device__ __forceinline__ float tanh_fast(float x) {
  float e = __expf(2.0f * x);
  return 1.0f - 2.0f / (e + 1.0f);
}
__device__ __forceinline__ unsigned int f2bf(float f) {
  unsigned int u = __float_as_uint(f);
  return (u + 0x7FFFu + ((u >> 16) & 1u)) >> 16;  // RNE
}
__device__ __forceinline__ unsigned int pack2(float lo, float hi) {
  return f2bf(lo) | (f2bf(hi) << 16);
}

// ---------------- Phase 0: fp32 [K][N] -> bf16 transposed [N][K] -------------
__global__ __launch_bounds__(256) void cvt_transpose(
    const float* __restrict__ src, unsigned short* __restrict__ dst) {
  __shared__ float t[32][33];
  const int bx = blockIdx.x * 32;
  const int by = blockIdx.y * 32;
  const int ty = threadIdx.x >> 3;
  const int tx = threadIdx.x & 7;
  float4 v = *(const float4*)&src[(size_t)(by + ty) * 1024 + bx + tx * 4];
  t[ty][tx * 4 + 0] = v.x; t[ty][tx * 4 + 1] = v.y;
  t[ty][tx * 4 + 2] = v.z; t[ty][tx * 4 + 3] = v.w;
  __syncthreads();
  ushort4 o;
  o.x = (unsigned short)f2bf(t[tx * 4 + 0][ty]);
  o.y = (unsigned short)f2bf(t[tx * 4 + 1][ty]);
  o.z = (unsigned short)f2bf(t[tx * 4 + 2][ty]);
  o.w = (unsigned short)f2bf(t[tx * 4 + 3][ty]);
  *(ushort4*)&dst[(size_t)(bx + ty) * 1024 + by + tx * 4] = o;
}

// ---------------- control clear (agent stores -> MALL) -----------------------
__global__ void clear_flags(unsigned int* flags) {
  __hip_atomic_store(&flags[threadIdx.x], 0u, __ATOMIC_RELAXED,
                     __HIP_MEMORY_SCOPE_AGENT);
}

// ---------------- Fused: GEMM producers + persistent scan --------------------
// flags[0..255]: scan member flags [c*32+m]. flags[256..259]: chunk counters.
// hbuf: [2 par][64 b][512 cp] dwords.
__global__ __launch_bounds__(512, 2) void fused(
    const float* __restrict__ X,             // [M][K] fp32
    const unsigned short* __restrict__ WxT,  // [N][K] bf16
    const unsigned short* __restrict__ WhT,  // [N][K] bf16
    const float* __restrict__ bx, const float* __restrict__ bh,
    float* __restrict__ out,                 // [B][T][H]
    float* __restrict__ hlast,               // [B][H]
    unsigned int* hbuf, unsigned int* flags) {
  __shared__ char smem[50176] __attribute__((aligned(16)));
  unsigned int* counters = flags + 256;
  const int bid = blockIdx.x;
  const int tid = threadIdx.x;
  const int w = tid >> 6;
  const int l = tid & 63;

  if (bid >= 64) {
    // ================= GEMM producer: 128x256 tile =================
    const int gid = bid - 64;        // 0..1023
    const int mt = gid >> 2;         // 0..255 : rows mt*128 (= batch mt>>2, chunk mt&3)
    const int np = gid & 3;          // col pair-block: cols np*256..+256
    const int m0 = mt * 128, n0 = np * 256;
    const int tc = mt & 3;
    char* const sA = smem;           // [128][64B]
    char* const sB = smem + 8192;    // [256][64B]
    const int half = w >> 2, w2 = w & 3;
    const int wm = (w2 >> 1) * 64, wn = half * 128 + (w2 & 1) * 64;
    const int rA = tid >> 2, kA = tid & 3;  // A: 128 rows x 4 segs (8 fp32)
    const int rB = tid >> 1, kB = tid & 1;  // B: 256 rows x 2 segs (16 bf16)

    f32x4 acc[4][4];
#pragma unroll
    for (int i = 0; i < 4; ++i)
#pragma unroll
      for (int j = 0; j < 4; ++j) acc[i][j] = (f32x4){0.f, 0.f, 0.f, 0.f};

    for (int k0 = 0; k0 < Idim; k0 += 32) {
      const float* xa = &X[(size_t)(m0 + rA) * Idim + k0 + kA * 8];
      float4 a0 = *(const float4*)xa, a1 = *(const float4*)(xa + 4);
      const char* wb =
          (const char*)&WxT[(size_t)(n0 + rB) * Idim + k0 + kB * 16];
      u32x4 b0 = *(const u32x4*)wb, b1 = *(const u32x4*)(wb + 16);
      __syncthreads();
      u32x4 pa = {pack2(a0.x, a0.y), pack2(a0.z, a0.w),
                  pack2(a1.x, a1.y), pack2(a1.z, a1.w)};
      *(u32x4*)(sA + ((rA * 64 + kA * 16) ^ ((rA & 7) << 4))) = pa;
      const int rbB = rB * 64 + kB * 32, swB = (rB & 7) << 4;
      *(u32x4*)(sB + (rbB ^ swB)) = b0;
      *(u32x4*)(sB + ((rbB + 16) ^ swB)) = b1;
      __syncthreads();
      bf16x8 af[4], bf[4];
#pragma unroll
      for (int i = 0; i < 4; ++i) {
        int ra = wm + i * 16 + (l & 15);
        af[i] = *(const bf16x8*)(sA + ((ra * 64 + (l >> 4) * 16) ^ ((ra & 7) << 4)));
        int rn = wn + i * 16 + (l & 15);
        bf[i] = *(const bf16x8*)(sB + ((rn * 64 + (l >> 4) * 16) ^ ((rn & 7) << 4)));
      }
#pragma unroll
      for (int i = 0; i < 4; ++i)
#pragma unroll
        for (int j = 0; j < 4; ++j)
          acc[i][j] = __builtin_amdgcn_mfma_f32_16x16x32_bf16(af[i], bf[j],
                                                              acc[i][j], 0, 0, 0);
    }
    float bias[4];
#pragma unroll
    for (int j = 0; j < 4; ++j) {
      int cc = n0 + wn + j * 16 + (l & 15);
      bias[j] = bx[cc] + bh[cc];
    }
    // C stores: sc0sc1 (write-through -> MALL-visible to scan blocks)
#pragma unroll
    for (int i = 0; i < 4; ++i) {
      int rbase = m0 + wm + i * 16 + (l >> 4) * 4;
#pragma unroll
      for (int j = 0; j < 4; ++j) {
        int cc = n0 + wn + j * 16 + (l & 15);
#pragma unroll
        for (int r = 0; r < 4; ++r) {
          float v = acc[i][j][r] + bias[j];
          float* p = &out[(size_t)(rbase + r) * Hdim + cc];
          asm volatile("global_store_dword %0, %1, off sc0 sc1"
                       :: "v"(p), "v"(v) : "memory");
        }
      }
    }
    asm volatile("s_waitcnt vmcnt(0)" ::: "memory");
    __syncthreads();  // all threads' stores drained
    if (tid == 0)
      __hip_atomic_fetch_add(&counters[tc], 1u, __ATOMIC_RELAXED,
                             __HIP_MEMORY_SCOPE_AGENT);
    return;
  }

  // ================= persistent scan (R9-fallback protocol) =================
  const int c = bid & 7;   // cluster: batches c*8..+8
  const int m = bid >> 3;  // member: cols m*128..+128
  const int n0 = m * 128;
  char* const smh = smem;          // h tile [8 b][2048 B], XOR-swizzled
  char* const smp = smem + 16384;  // partials [8 w][8 nt][33][16 B]

  // B-frags: Wh[k=w*128..+128][cols n0..+128] = 32 x bf16x8
  bf16x8 bfrag[32];
  {
    const int kb = (w << 7) + ((l >> 4) << 3);
    const int col = n0 + (l & 15);
#pragma unroll
    for (int nt = 0; nt < 8; ++nt)
#pragma unroll
      for (int kt = 0; kt < 4; ++kt)
        bfrag[nt * 4 + kt] =
            *(const bf16x8*)&WhT[(size_t)(col + nt * 16) * 1024 + kb + kt * 32];
  }

  const int c0 = l * 2;  // col pair this thread finishes
  const int b_abs = c * 8 + w;
  const int nt0 = c0 >> 4;
  const int lane0 = ((w >> 2) << 4) | (c0 & 15);
  const int regb = (w & 3) * 4;
  const size_t orow = (size_t)b_abs * ((size_t)Tdim * Hdim) + n0 + c0;
  unsigned int* const myflag = &flags[c * 32 + m];
  const unsigned int* const pollf = &flags[c * 32 + (l & 7)];

  // gate: wait until xproj chunk tc2 fully stored (256 tiles) at the MALL
  auto gate = [&](int tc2) {
    if (tid == 0) {
      const unsigned int* cp = &counters[tc2];
      for (;;) {
        unsigned int v;
        asm volatile(
            "global_load_dword %0, %1, off sc0 sc1\n\ts_waitcnt vmcnt(0)"
            : "=v"(v) : "v"(cp) : "memory");
        if (v >= 256u) break;
        __builtin_amdgcn_s_sleep(16);
      }
    }
    __syncthreads();
  };

  gate(0);
  float2 xp = *(const float2*)&out[orow];  // xproj t=0 (post-gate: fresh)

  for (int t = 0; t < Tdim; ++t) {
    float sum0 = 0.f, sum1 = 0.f;
    if (t > 0) {
      const int arow = l & 7;
      const int ab = arow * 2048 + (w << 8) + ((l >> 4) << 4);
      const int sw2 = arow << 4;
      bf16x8 af0 = *(const bf16x8*)(smh + ((ab + 0) ^ sw2));
      bf16x8 af1 = *(const bf16x8*)(smh + ((ab + 64) ^ sw2));
      bf16x8 af2 = *(const bf16x8*)(smh + ((ab + 128) ^ sw2));
      bf16x8 af3 = *(const bf16x8*)(smh + ((ab + 192) ^ sw2));
#pragma unroll
      for (int nt = 0; nt < 8; ++nt) {
        f32x4 a = {0.f, 0.f, 0.f, 0.f};
        a = __builtin_amdgcn_mfma_f32_16x16x32_bf16(af0, bfrag[nt * 4 + 0], a, 0, 0, 0);
        a = __builtin_amdgcn_mfma_f32_16x16x32_bf16(af1, bfrag[nt * 4 + 1], a, 0, 0, 0);
        a = __builtin_amdgcn_mfma_f32_16x16x32_bf16(af2, bfrag[nt * 4 + 2], a, 0, 0, 0);
        a = __builtin_amdgcn_mfma_f32_16x16x32_bf16(af3, bfrag[nt * 4 + 3], a, 0, 0, 0);
        if (l < 32)  // lanes 32-63 hold duplicate batch rows: discard
          *(f32x4*)(smp + (((w * 8 + nt) * 33 + l) << 4)) = a;
      }
      asm volatile("s_waitcnt lgkmcnt(0)" ::: "memory");
      __builtin_amdgcn_s_barrier();  // #P: partials visible
      asm volatile("" ::: "memory");
#pragma unroll
      for (int w8 = 0; w8 < 8; ++w8) {
        const char* p = smp + (((w8 * 8 + nt0) * 33 + lane0) << 4) + regb;
        sum0 += *(const float*)p;
        sum1 += *(const float*)(p + 16);
      }
    }
    float h0 = tanh_fast(xp.x + sum0);
    float h1 = tanh_fast(xp.y + sum1);
    if (t == Tdim - 1) {
      *(float2*)&out[orow + (size_t)t * Hdim] = make_float2(h0, h1);
      *(float2*)&hlast[(size_t)b_abs * Hdim + n0 + c0] = make_float2(h0, h1);
      break;
    }
    if (((t + 1) & 127) == 0) gate((t + 1) >> 7);  // before xp(t+1) prefetch
    const int par = (t + 1) & 1;
    const unsigned int tp1 = (unsigned int)(t + 1);
    // publish FIRST; out-store + xp-prefetch float behind it (R7 queue)
    __hip_atomic_store(&hbuf[(size_t)par * 32768 + (size_t)b_abs * 512 +
                             m * 64 + l],
                       pack2(h0, h1), __ATOMIC_RELAXED,
                       __HIP_MEMORY_SCOPE_AGENT);
    asm volatile("" ::: "memory");
    *(float2*)&out[orow + (size_t)t * Hdim] = make_float2(h0, h1);
    xp = *(const float2*)&out[orow + (size_t)(t + 1) * Hdim];
    // queue: [publish, out, xp] -> vmcnt(2) == publish acked at MALL
    asm volatile("s_waitcnt vmcnt(2)" ::: "memory");
    __builtin_amdgcn_s_barrier();  // #B: all publishes acked
    asm volatile("" ::: "memory");
    if (tid == 0)
      __hip_atomic_store(myflag, tp1, __ATOMIC_RELAXED,
                         __HIP_MEMORY_SCOPE_AGENT);
    if (w == 7) {  // poll 8 member flags (one 128B line per cluster)
      for (;;) {
        unsigned int v;
        asm volatile(
            "global_load_dword %0, %1, off sc0 sc1\n\ts_waitcnt vmcnt(0)"
            : "=v"(v) : "v"(pollf) : "memory");
        if (__ballot(v >= tp1) == ~0ull) break;
        __builtin_amdgcn_s_sleep(2);
      }
    }
    asm volatile("" ::: "memory");
    __builtin_amdgcn_s_barrier();  // #C: flags observed
    asm volatile("" ::: "memory");
    // stage tile for t+1: MALL loads only, self-drained
    {
      const char* srcp = (const char*)hbuf + (size_t)par * 131072 +
                         (size_t)b_abs * 2048 + l * 32;
      u32x4 d0, d1;
      asm volatile(
          "global_load_dwordx4 %0, %2, off sc0 sc1\n\t"
          "global_load_dwordx4 %1, %2, off offset:16 sc0 sc1\n\t"
          "s_waitcnt vmcnt(0)"
          : "=&v"(d0), "=&v"(d1) : "v"(srcp) : "memory");
      __builtin_amdgcn_sched_barrier(0);
      const int base = w * 2048 + l * 32;
      const int swz = w << 4;
      *(u32x4*)(smh + (base ^ swz)) = d0;
      *(u32x4*)(smh + ((base + 16) ^ swz)) = d1;
    }
    asm volatile("s_waitcnt lgkmcnt(0)" ::: "memory");
    __builtin_amdgcn_s_barrier();  // #D: tile staged
    asm volatile("" ::: "memory");
  }
}

extern "C" void kernel_launch(void* const* d_in, const int* in_sizes, int n_in,
                              void* d_out, int out_size, void* d_ws,
                              size_t ws_size, hipStream_t stream) {
  const float* x  = (const float*)d_in[0];
  const float* Wx = (const float*)d_in[1];
  const float* bx = (const float*)d_in[2];
  const float* Wh = (const float*)d_in[3];
  const float* bh = (const float*)d_in[4];
  float* out = (float*)d_out;
  float* hlast = out + (size_t)Bdim * Tdim * Hdim;
  unsigned int* flags = (unsigned int*)d_ws;                       // 2 KB
  unsigned int* hbuf = (unsigned int*)((char*)d_ws + 4096);        // 256 KB
  unsigned short* WxT = (unsigned short*)((char*)d_ws + 4096 + 262144);
  unsigned short* WhT = (unsigned short*)((char*)d_ws + 4096 + 262144 + 2097152);

  clear_flags<<<1, dim3(512), 0, stream>>>(flags);
  dim3 gt(32, 32);
  cvt_transpose<<<gt, dim3(256), 0, stream>>>(Wx, WxT);
  cvt_transpose<<<gt, dim3(256), 0, stream>>>(Wh, WhT);
  fused<<<dim3(64 + 1024), dim3(512), 0, stream>>>(x, WxT, WhT, bx, bh, out,
                                                   hlast, hbuf, flags);
}